// Round 1
// baseline (683.719 us; speedup 1.0000x reference)
//
#include <hip/hip_runtime.h>

#define RADIUS 2
#define TH 8   // output rows per thread (H=512 divisible)
#define LOG2E 1.4426950408889634f

#if __has_builtin(__builtin_amdgcn_exp2f)
#define EXP2(x) __builtin_amdgcn_exp2f(x)
#else
#define EXP2(x) exp2f(x)
#endif

// 16B vector load with only 4B alignment guarantee (row base is 12B-aligned).
typedef float f4 __attribute__((ext_vector_type(4), aligned(4)));

__device__ __forceinline__ void load15(float dst[15], const float* p) {
    f4 a = *(const f4*)(p + 0);
    f4 b = *(const f4*)(p + 4);
    f4 c = *(const f4*)(p + 8);
    dst[0] = a.x;  dst[1] = a.y;  dst[2]  = a.z;  dst[3]  = a.w;
    dst[4] = b.x;  dst[5] = b.y;  dst[6]  = b.z;  dst[7]  = b.w;
    dst[8] = c.x;  dst[9] = c.y;  dst[10] = c.z;  dst[11] = c.w;
    dst[12] = p[12]; dst[13] = p[13]; dst[14] = p[14];
}

// 25-tap bilateral for one pixel from a register-resident 5x15 window.
// Weights in exp2 domain: w = exp2(-50*log2e*cdist2 - 0.5*log2e*sdist2).
__device__ __forceinline__ void bilateral_px(const float win[5][15], float* outp) {
    const float cr = win[2][6], cg = win[2][7], cb = win[2][8];
    float numr = 0.f, numg = 0.f, numb = 0.f, den = 0.f;
#pragma unroll
    for (int dy = 0; dy < 5; ++dy) {
#pragma unroll
        for (int dx = 0; dx < 5; ++dx) {
            const float nr = win[dy][3 * dx + 0];
            const float ng = win[dy][3 * dx + 1];
            const float nb = win[dy][3 * dx + 2];
            if (dy == 2 && dx == 2) {
                // center tap: cdist2 == 0, spatial == 0 -> w == 1 exactly
                numr += cr; numg += cg; numb += cb; den += 1.0f;
            } else {
                const float dr = nr - cr, dg = ng - cg, db = nb - cb;
                float cd = dr * dr;
                cd = fmaf(dg, dg, cd);
                cd = fmaf(db, db, cd);
                const float spatial =
                    -0.5f * LOG2E * (float)((dy - 2) * (dy - 2) + (dx - 2) * (dx - 2));
                const float arg = fmaf(cd, -50.0f * LOG2E, spatial);
                const float w = EXP2(arg);
                numr = fmaf(w, nr, numr);
                numg = fmaf(w, ng, numg);
                numb = fmaf(w, nb, numb);
                den += w;
            }
        }
    }
    const float inv = __builtin_amdgcn_rcpf(den);   // den >= 1
    outp[0] = numr * inv;
    outp[1] = numg * inv;
    outp[2] = numb * inv;
}

// One thread per (batch, column, 8-row tile). launch_bounds(256,4): 128-VGPR
// budget so the 75-float sliding window stays register-resident (the previous
// 64-VGPR clamp forced the compiler to rematerialize it as cache re-loads).
__global__ __launch_bounds__(256, 4) void bilateral_kernel(
    const float* __restrict__ x, float* __restrict__ out,
    int B, int H, int W)
{
    const int tid = blockIdx.x * blockDim.x + threadIdx.x;
    const int tilesPerCol = H / TH;
    const int total = B * W * tilesPerCol;
    if (tid >= total) return;

    const int wslot = tid % W;
    // rotate columns by +RADIUS: edge columns {0,1,W-2,W-1} all land in the
    // LAST 64-lane wave of each 512-column group -> only 1 of 8 column-waves
    // (plus the t=0 / t=last row-tiles) takes the guarded slow path.
    const int w0 = (wslot + RADIUS) % W;
    const int t  = (tid / W) % tilesPerCol;
    const int b0 = tid / (W * tilesPerCol);
    const int h0 = t * TH;

    const float* __restrict__ img = x + (size_t)b0 * H * W * 3;
    float* __restrict__ oimg      = out + (size_t)b0 * H * W * 3;
    const int rs = W * 3;

    const bool fastlane = (t >= 1) && (t <= tilesPerCol - 2) &&
                          (w0 >= RADIUS) && (w0 < W - RADIUS);

    if (__all(fastlane)) {
        // ---- interior fast path: unconditional vector loads, pipelined ----
        float win[5][15];
        const float* p = img + ((h0 - 2) * W + (w0 - RADIUS)) * 3;
        load15(win[0], p); p += rs;
        load15(win[1], p); p += rs;
        load15(win[2], p); p += rs;
        load15(win[3], p); p += rs;
        load15(win[4], p); p += rs;

        float* op = oimg + (h0 * W + w0) * 3;
#pragma unroll
        for (int i = 0; i < TH; ++i) {
            float nxt[15];
            if (i < TH - 1) {            // issue row h0+i+3 BEFORE tap math:
                load15(nxt, p);          // ~250 VALU cycles hide the latency
                p += rs;
            }
            bilateral_px(win, op);
            op += rs;
            if (i < TH - 1) {
#pragma unroll
                for (int rr = 0; rr < 4; ++rr)
#pragma unroll
                    for (int j = 0; j < 15; ++j) win[rr][j] = win[rr + 1][j];
#pragma unroll
                for (int j = 0; j < 15; ++j) win[4][j] = nxt[j];
            }
        }
    } else {
        // ---- boundary slow path: per-element guards (~15% of waves) ----
        bool cok[5];
#pragma unroll
        for (int j = 0; j < 5; ++j) {
            const int ww = w0 - RADIUS + j;
            cok[j] = (ww >= 0) && (ww < W);
        }
        float win[5][15];

#define LOAD_ROW_G(ri, hh_)                                                \
        {                                                                  \
            const int hh = (hh_);                                          \
            const bool rowok = (hh >= 0) && (hh < H);                      \
            const int base = (hh * W + (w0 - RADIUS)) * 3;                 \
            _Pragma("unroll")                                              \
            for (int j = 0; j < 5; ++j) {                                  \
                const bool ok = rowok && cok[j];                           \
                _Pragma("unroll")                                          \
                for (int c = 0; c < 3; ++c)                                \
                    win[ri][3 * j + c] = ok ? img[base + 3 * j + c] : 0.0f;\
            }                                                              \
        }

        LOAD_ROW_G(0, h0 - 2)
        LOAD_ROW_G(1, h0 - 1)
        LOAD_ROW_G(2, h0 + 0)
        LOAD_ROW_G(3, h0 + 1)

        float* op = oimg + (h0 * W + w0) * 3;
#pragma unroll
        for (int i = 0; i < TH; ++i) {
            LOAD_ROW_G(4, h0 + i + 2)
            bilateral_px(win, op);
            op += rs;
            if (i < TH - 1) {
#pragma unroll
                for (int rr = 0; rr < 4; ++rr)
#pragma unroll
                    for (int j = 0; j < 15; ++j) win[rr][j] = win[rr + 1][j];
            }
        }
#undef LOAD_ROW_G
    }
}

extern "C" void kernel_launch(void* const* d_in, const int* in_sizes, int n_in,
                              void* d_out, int out_size, void* d_ws, size_t ws_size,
                              hipStream_t stream) {
    const float* x = (const float*)d_in[0];
    float* out = (float*)d_out;

    const int B = 16, H = 512, W = 512;
    const int total = B * W * (H / TH);
    const int block = 256;
    const int grid = (total + block - 1) / block;

    bilateral_kernel<<<grid, block, 0, stream>>>(x, out, B, H, W);
}

// Round 2
// 51.936 us; speedup vs baseline: 13.1645x; 13.1645x over previous
//
#include <hip/hip_runtime.h>

#define RADIUS 2
#define TH 4                 // output rows per thread; live set must fit 64 VGPRs
#define LOG2E 1.4426950408889634f
#define NEG50L (-50.0f * LOG2E)   // -0.5 * (1/sigma_color^2) * log2(e)

// compile-time problem shape (bench is fixed at 16x512x512x3 f32 NHWC)
#define B_ 16
#define H_ 512
#define W_ 512
#define TILES (H_ / TH)      // 128
#define RS (W_ * 3)          // row stride in floats

#if __has_builtin(__builtin_amdgcn_exp2f)
#define EXP2(x) __builtin_amdgcn_exp2f(x)
#else
#define EXP2(x) exp2f(x)
#endif

// 16B vector load with only 4B alignment guarantee (row base is 12B-aligned).
typedef float f4 __attribute__((ext_vector_type(4), aligned(4)));

__device__ __forceinline__ void load15(float d[15], const float* __restrict__ p) {
    f4 a = *(const f4*)(p + 0);
    f4 b = *(const f4*)(p + 4);
    f4 c = *(const f4*)(p + 8);
    f4 e = *(const f4*)(p + 11);      // overlaps c.w; keeps it 4 VMEM instrs
    d[0] = a.x;  d[1] = a.y;  d[2]  = a.z;  d[3]  = a.w;
    d[4] = b.x;  d[5] = b.y;  d[6]  = b.z;  d[7]  = b.w;
    d[8] = c.x;  d[9] = c.y;  d[10] = c.z;  d[11] = e.x;
    d[12] = e.y; d[13] = e.z; d[14] = e.w;
}

// 5 taps of one window row (row offset dy in 0..4, constant after unroll)
// for one center pixel. Center tap (dy==2,dx==2) is pre-folded into the
// accumulator init, so it's skipped here.
__device__ __forceinline__ void taps_row(const float row[15], int dy,
                                         float cr, float cg, float cb,
                                         float& ar, float& ag, float& ab,
                                         float& ad) {
    const int sdy = (dy - 2) * (dy - 2);
#pragma unroll
    for (int dx = 0; dx < 5; ++dx) {
        if (dy == 2 && dx == 2) continue;   // folds away (dy is unroll-const)
        const float nr = row[3 * dx + 0];
        const float ng = row[3 * dx + 1];
        const float nb = row[3 * dx + 2];
        const float dr = nr - cr, dg = ng - cg, db = nb - cb;
        float cd = dr * dr;
        cd = fmaf(dg, dg, cd);
        cd = fmaf(db, db, cd);
        const float spatial =
            -0.5f * LOG2E * (float)(sdy + (dx - 2) * (dx - 2));
        const float w = EXP2(fmaf(cd, NEG50L, spatial));
        ar = fmaf(w, nr, ar);
        ag = fmaf(w, ng, ag);
        ab = fmaf(w, nb, ab);
        ad += w;
    }
}

// One thread = (batch, column, 4-row tile). Streams 8 input rows; each row
// feeds the windows of all 4 output pixels -> only ONE 15-float row is live
// at a time (peak live ~55 floats, fits the 64-VGPR / 8-wave occupancy tier).
__global__ __launch_bounds__(256) void bilateral_kernel(
    const float* __restrict__ x, float* __restrict__ out)
{
    const int tid = blockIdx.x * blockDim.x + threadIdx.x;
    const int wslot = tid & (W_ - 1);
    // rotate columns by +RADIUS: edge columns {0,1,510,511} all land in the
    // last 64-lane wave of each 512-column group -> 7 of 8 column-waves are
    // unguarded fast path.
    const int w0 = (wslot + RADIUS) & (W_ - 1);
    const int t  = (tid >> 9) & (TILES - 1);
    const int b0 = tid >> 16;
    const int h0 = t * TH;

    const float* __restrict__ img = x + (size_t)b0 * (H_ * W_ * 3);
    float* __restrict__ oimg      = out + (size_t)b0 * (H_ * W_ * 3);

    // centers: always in-bounds (rows h0..h0+3, column w0)
    float cc[TH][3];
#pragma unroll
    for (int j = 0; j < TH; ++j) {
        const float* cp = img + ((h0 + j) * W_ + w0) * 3;
        cc[j][0] = cp[0]; cc[j][1] = cp[1]; cc[j][2] = cp[2];
    }
    // accumulators, center tap (w==1) pre-folded
    float acc[TH][4];
#pragma unroll
    for (int j = 0; j < TH; ++j) {
        acc[j][0] = cc[j][0];
        acc[j][1] = cc[j][1];
        acc[j][2] = cc[j][2];
        acc[j][3] = 1.0f;
    }

    const bool fast = (t >= 1) && (t <= TILES - 2) &&
                      (w0 >= RADIUS) && (w0 < W_ - RADIUS);

    if (__all(fast)) {
        // interior: unconditional vector row loads
        const float* p = img + ((h0 - 2) * W_ + (w0 - RADIUS)) * 3;
#pragma unroll
        for (int r = 0; r < TH + 4; ++r) {
            float row[15];
            load15(row, p);
            p += RS;
#pragma unroll
            for (int j = 0; j < TH; ++j) {
                if (r - j >= 0 && r - j <= 4)   // unroll-const condition
                    taps_row(row, r - j, cc[j][0], cc[j][1], cc[j][2],
                             acc[j][0], acc[j][1], acc[j][2], acc[j][3]);
            }
        }
    } else {
        // boundary (~14% of waves): per-element guarded loads; OOB taps use
        // nbr=0 but still contribute weight to den (skimage constant mode).
        bool cok[5];
#pragma unroll
        for (int jj = 0; jj < 5; ++jj) {
            const int ww = w0 - RADIUS + jj;
            cok[jj] = (ww >= 0) && (ww < W_);
        }
#pragma unroll
        for (int r = 0; r < TH + 4; ++r) {
            const int hh = h0 - 2 + r;
            const bool rowok = (hh >= 0) && (hh < H_);
            const int base = (hh * W_ + (w0 - RADIUS)) * 3;
            float row[15];
#pragma unroll
            for (int jj = 0; jj < 5; ++jj) {
                const bool ok = rowok && cok[jj];
#pragma unroll
                for (int c = 0; c < 3; ++c)
                    row[3 * jj + c] = ok ? img[base + 3 * jj + c] : 0.0f;
            }
#pragma unroll
            for (int j = 0; j < TH; ++j) {
                if (r - j >= 0 && r - j <= 4)
                    taps_row(row, r - j, cc[j][0], cc[j][1], cc[j][2],
                             acc[j][0], acc[j][1], acc[j][2], acc[j][3]);
            }
        }
    }

#pragma unroll
    for (int j = 0; j < TH; ++j) {
        const float inv = __builtin_amdgcn_rcpf(acc[j][3]);   // den >= 1
        float* op = oimg + ((h0 + j) * W_ + w0) * 3;
        op[0] = acc[j][0] * inv;
        op[1] = acc[j][1] * inv;
        op[2] = acc[j][2] * inv;
    }
}

extern "C" void kernel_launch(void* const* d_in, const int* in_sizes, int n_in,
                              void* d_out, int out_size, void* d_ws, size_t ws_size,
                              hipStream_t stream) {
    const float* x = (const float*)d_in[0];
    float* out = (float*)d_out;

    const int total = B_ * W_ * TILES;      // 1,048,576 (exact multiple of 256)
    const int block = 256;
    const int grid = total / block;

    bilateral_kernel<<<grid, block, 0, stream>>>(x, out);
}